// Round 2
// baseline (119.267 us; speedup 1.0000x reference)
//
#include <hip/hip_runtime.h>
#include <math.h>

// B=8, C=64, H=W=64, O=64, K=3, KK=9, HW=4096
// Fully fused formulation, mfma_f32_16x16x32_bf16 (bf16 in, fp32 acc).
// One wave owns 16 pixels (one h-row segment) and computes om (K=1152) then
// the deformable conv (K=576) with NO cross-wave communication.
// Operand orientation (HW-validated in earlier rounds):
//   A = weights:  lane(l16,lq) holds W[m = tile*16+l16][k = step*32+lq*8+j]
//   B = samples:  lane(l16,lq) holds S[k = step*32+lq*8+j][n = px(l16)]
//   C/D: col(=px) = lane&15, row(=m) = (lane>>4)*4 + reg
//
// ws layout (shorts):
//   [0,     36864)  wd_pk : Wd A-frag-packed, idx=((ks*4+lq)*64+o)*8+j,
//                   ks=t*2+qh (18), k=t*64+qh*32+lq*8+j -> weight[o][c][t]
//   [36864, 73728)  wo_pk : Wo A-frag-packed, idx=((ks2*4+lq)*32+oc)*8+j,
//                   ks2=quarter*9+t (36), cg=quarter*32+lq*8+j; oc>=27 -> 0
//   [73728, 73728+4194304)  catT bf16[b][hw][128]  (feat c0..63, deg c64..127)
//
// R2: reverted R0's lwd LDS staging (72KB LDS capped occupancy at 2 waves/SIMD
// and cancelled its L2-traffic win; A-frags are L2-resident streams anyway).
// LDS back to 7.2KB -> ~3 waves/SIMD. Kept: cvt_pk pairwise blend, merged
// prep. New: all 8 corner gathers of a tap issued before blending (2x MLP).
#define WO_PK_OFF 36864
#define CATT_OFF  73728

typedef short  short8  __attribute__((ext_vector_type(8)));
typedef float  float4v __attribute__((ext_vector_type(4)));
typedef unsigned int uint4v __attribute__((ext_vector_type(4)));

static __device__ __forceinline__ short f2bf(float f) {
    unsigned int u = __builtin_bit_cast(unsigned int, f);
    u += 0x7FFFu + ((u >> 16) & 1u);   // round-to-nearest-even
    return (short)(u >> 16);
}
static __device__ __forceinline__ float bf2f(unsigned short u) {
    return __builtin_bit_cast(float, (unsigned int)u << 16);
}
// pack 2 fp32 -> 2 bf16 (RNE), one instruction. lo -> D[15:0], hi -> D[31:16]
static __device__ __forceinline__ unsigned int cvt_pk_bf16(float lo, float hi) {
    unsigned int r;
    asm("v_cvt_pk_bf16_f32 %0, %1, %2" : "=v"(r) : "v"(lo), "v"(hi));
    return r;
}

// Merged prep: blocks [0,512) transpose catT, blocks [512,800) pack weights.
// Transpose: block=(b,h): 64 pixels x 128 channels, LDS round-trip, row pad
// 136 shorts (16B-aligned b128 reads, ~2-way banks).
__global__ __launch_bounds__(256) void prep_kernel(
    const float* __restrict__ feat, const float* __restrict__ deg,
    unsigned short* __restrict__ catT,
    const float* __restrict__ weight, const float* __restrict__ om_weight,
    short* __restrict__ wd_pk, short* __restrict__ wo_pk)
{
    __shared__ unsigned short T[64 * 136];     // 17,408 B
    const int tid = threadIdx.x;

    if (blockIdx.x >= 512) {                   // ---- weight packing ----
        int idx = (blockIdx.x - 512) * 256 + tid;   // covers exactly 73728
        if (idx < 36864) {
            int j = idx & 7, o = (idx >> 3) & 63, lq = (idx >> 9) & 3, ks = idx >> 11;
            int t = ks >> 1, c = (ks & 1) * 32 + lq * 8 + j;
            wd_pk[idx] = f2bf(weight[(o * 64 + c) * 9 + t]);
        } else {
            int e = idx - 36864;
            int j = e & 7, oc = (e >> 3) & 31, lq = (e >> 8) & 3, ks2 = e >> 10;
            int quarter = ks2 / 9, t = ks2 - quarter * 9;
            int cg = quarter * 32 + lq * 8 + j;
            wo_pk[e] = (oc < 27) ? f2bf(om_weight[(oc * 128 + cg) * 9 + t])
                                 : (short)0;
        }
        return;
    }

    // ---- transpose ----
    const int b = blockIdx.x >> 6, h = blockIdx.x & 63;
    const int lane = tid & 63, wv = tid >> 6;
#pragma unroll
    for (int cc = 0; cc < 32; cc++) {
        int c = wv * 32 + cc;                  // wave-uniform
        const float* src = (c < 64)
            ? (feat + (size_t)(b * 64 + c) * 4096)
            : (deg  + (size_t)(b * 64 + (c - 64)) * 4096);
        T[lane * 136 + c] = (unsigned short)f2bf(src[h * 64 + lane]);
    }
    __syncthreads();
    const int px = tid >> 2, seg = tid & 3;
    unsigned short* dst = catT + (size_t)(b * 4096 + h * 64 + px) * 128 + seg * 32;
#pragma unroll
    for (int j = 0; j < 4; j++)
        *(uint4*)(dst + j * 8) = *(const uint4*)&T[px * 136 + seg * 32 + j * 8];
}

// The fused kernel. gw = wave id in [0,2048): b = gw>>8, 16-px tile = gw&255.
// Phase 1 (omconv): 36 K-steps, 2 MFMAs each. Phase 2: wave-private LDS
// transpose C-layout -> per-pixel omv[27] (+bias), one barrier. Phase 3
// (deform): 9 taps; all 8 corner gathers issued up front, then 2 ch-halves:
// pairwise bilinear on bf16 catT, cvt_pk pack, 4 MFMAs (A-frags from global,
// L2-resident affine stream).
__global__ __launch_bounds__(256) void fused_kernel(
    const unsigned short* __restrict__ catT, const short* __restrict__ wd_pk,
    const short* __restrict__ wo_pk, const float* __restrict__ om_bias,
    float* __restrict__ out)
{
    __shared__ __align__(16) float Tsm[4 * 448]; // 7,168 B (per-wave 16x28)
    const int tid = threadIdx.x;
    const int lane = tid & 63, wv = tid >> 6;
    const int l16 = lane & 15, lq = lane >> 4;
    const int gw = blockIdx.x * 4 + wv;
    const int b = gw >> 8, tile = gw & 255;
    const int h = tile >> 2, w0 = (tile & 3) << 4;
    const int pxx = w0 + l16;                  // this lane's pixel x
    const unsigned short* cb = catT + (size_t)b * 4096 * 128;

    // ---------------- phase 1: om conv ----------------
    float4v oacc0 = {0.f, 0.f, 0.f, 0.f};
    float4v oacc1 = {0.f, 0.f, 0.f, 0.f};
    const short8 zf = {0, 0, 0, 0, 0, 0, 0, 0};
#pragma unroll
    for (int quarter = 0; quarter < 4; quarter++) {
#pragma unroll
        for (int t = 0; t < 9; t++) {
            const int ky = t / 3, kx = t - ky * 3;
            const int yy = h - 1 + ky;         // wave-uniform
            if (yy >= 0 && yy <= 63) {
                int xx = pxx - 1 + kx;
                bool okx = (xx >= 0) & (xx <= 63);
                int xc = min(max(xx, 0), 63);
                short8 bfr = *(const short8*)(cb + (yy * 64 + xc) * 128
                                                 + quarter * 32 + lq * 8);
                bfr = okx ? bfr : zf;
                const short8* Ap = (const short8*)(wo_pk
                    + (size_t)((quarter * 9 + t) * 4 + lq) * 256);
                oacc0 = __builtin_amdgcn_mfma_f32_16x16x32_bf16(
                    Ap[l16], bfr, oacc0, 0, 0, 0);
                oacc1 = __builtin_amdgcn_mfma_f32_16x16x32_bf16(
                    Ap[16 + l16], bfr, oacc1, 0, 0, 0);
            }
        }
    }

    // ------- phase 2: wave-private transpose -> omv[27] -------
    float* Tw = Tsm + wv * 448;                // 16 rows x 28 floats
#pragma unroll
    for (int r = 0; r < 4; r++) {
        Tw[l16 * 28 + lq * 4 + r] = oacc0[r];             // oc = lq*4+r
        if (lq < 3)
            Tw[l16 * 28 + 16 + lq * 4 + r] = oacc1[r];    // oc = 16+lq*4+r <= 27
    }
    __syncthreads();                            // orders intra-wave LDS w->r
    float omv[28];
#pragma unroll
    for (int jj = 0; jj < 7; jj++)
        *(float4v*)&omv[jj * 4] = *(const float4v*)&Tw[l16 * 28 + jj * 4];
#pragma unroll
    for (int j = 0; j < 27; j++) omv[j] += om_bias[j];

    // ---------------- phase 3: deformable conv ----------------
    float4v acc[4];
#pragma unroll
    for (int mt = 0; mt < 4; mt++) acc[mt] = (float4v){0.f, 0.f, 0.f, 0.f};
#pragma unroll
    for (int t = 0; t < 9; t++) {
        const int ky = t / 3, kx = t - ky * 3;
        float dy = omv[2 * t], dx = omv[2 * t + 1];
        float mm = 1.f / (1.f + __expf(-omv[18 + t]));   // sigmoid(mask)
        float yf = (float)(h - 1 + ky) + dy;
        float xf = (float)(pxx - 1 + kx) + dx;
        float fy = floorf(yf), fx = floorf(xf);
        int y0 = (int)fy, x0 = (int)fx;
        float wy = yf - fy, wx = xf - fx;
        bool vy0 = (y0 >= 0) & (y0 < 64);
        bool vy1 = (y0 >= -1) & (y0 < 63);
        bool vx0 = (x0 >= 0) & (x0 < 64);
        bool vx1 = (x0 >= -1) & (x0 < 63);
        float a0 = (1.f - wy) * mm, a1 = wy * mm;
        float W00 = a0 * (1.f - wx) * (float)(vy0 & vx0);
        float W01 = a0 * wx         * (float)(vy0 & vx1);
        float W10 = a1 * (1.f - wx) * (float)(vy1 & vx0);
        float W11 = a1 * wx         * (float)(vy1 & vx1);
        // taps clamped INDEPENDENTLY: clamp(y0+1), not clamp(y0)+1
        int iy0 = min(max(y0, 0), 63),     ix0 = min(max(x0, 0), 63);
        int iy1 = min(max(y0 + 1, 0), 63), ix1 = min(max(x0 + 1, 0), 63);
        int O00 = (iy0 * 64 + ix0) * 128, O01 = (iy0 * 64 + ix1) * 128;
        int O10 = (iy1 * 64 + ix0) * 128, O11 = (iy1 * 64 + ix1) * 128;

        // issue ALL 8 corner gathers (both ch-halves) before blending: 8
        // scattered b128 loads in flight instead of 4 halves latency exposure
        uint4v u0[4], u1[4];
        {
            const int c0 = lq * 8, c1 = 32 + lq * 8;
            u0[0] = *(const uint4v*)(cb + O00 + c0);
            u0[1] = *(const uint4v*)(cb + O01 + c0);
            u0[2] = *(const uint4v*)(cb + O10 + c0);
            u0[3] = *(const uint4v*)(cb + O11 + c0);
            u1[0] = *(const uint4v*)(cb + O00 + c1);
            u1[1] = *(const uint4v*)(cb + O01 + c1);
            u1[2] = *(const uint4v*)(cb + O10 + c1);
            u1[3] = *(const uint4v*)(cb + O11 + c1);
        }
#pragma unroll
        for (int qh = 0; qh < 2; qh++) {
            uint4v u00 = qh ? u1[0] : u0[0];
            uint4v u01 = qh ? u1[1] : u0[1];
            uint4v u10 = qh ? u1[2] : u0[2];
            uint4v u11 = qh ? u1[3] : u0[3];
            uint4v br;
#pragma unroll
            for (int p = 0; p < 4; p++) {   // channel pair (2p lo, 2p+1 hi)
                float l00 = __builtin_bit_cast(float, u00[p] << 16);
                float h00 = __builtin_bit_cast(float, u00[p] & 0xffff0000u);
                float l01 = __builtin_bit_cast(float, u01[p] << 16);
                float h01 = __builtin_bit_cast(float, u01[p] & 0xffff0000u);
                float l10 = __builtin_bit_cast(float, u10[p] << 16);
                float h10 = __builtin_bit_cast(float, u10[p] & 0xffff0000u);
                float l11 = __builtin_bit_cast(float, u11[p] << 16);
                float h11 = __builtin_bit_cast(float, u11[p] & 0xffff0000u);
                float slo = W00 * l00 + W01 * l01 + W10 * l10 + W11 * l11;
                float shi = W00 * h00 + W01 * h01 + W10 * h10 + W11 * h11;
                br[p] = cvt_pk_bf16(slo, shi);
            }
            short8 bfr = __builtin_bit_cast(short8, br);
            const short8* Dp = (const short8*)(wd_pk
                + (size_t)((t * 2 + qh) * 4 + lq) * 512);
            acc[0] = __builtin_amdgcn_mfma_f32_16x16x32_bf16(
                Dp[l16], bfr, acc[0], 0, 0, 0);
            acc[1] = __builtin_amdgcn_mfma_f32_16x16x32_bf16(
                Dp[16 + l16], bfr, acc[1], 0, 0, 0);
            acc[2] = __builtin_amdgcn_mfma_f32_16x16x32_bf16(
                Dp[32 + l16], bfr, acc[2], 0, 0, 0);
            acc[3] = __builtin_amdgcn_mfma_f32_16x16x32_bf16(
                Dp[48 + l16], bfr, acc[3], 0, 0, 0);
        }
    }

    // store: o = mt*16 + lq*4 + r, px = w0 + l16 (4-seg coalesced)
    float* ob = out + (size_t)(b * 64) * 4096 + h * 64 + w0 + l16;
#pragma unroll
    for (int mt = 0; mt < 4; mt++)
#pragma unroll
        for (int r = 0; r < 4; r++)
            ob[(mt * 16 + lq * 4 + r) * 4096] = acc[mt][r];
}

extern "C" void kernel_launch(void* const* d_in, const int* in_sizes, int n_in,
                              void* d_out, int out_size, void* d_ws, size_t ws_size,
                              hipStream_t stream)
{
    const float* feat      = (const float*)d_in[0];
    const float* deg       = (const float*)d_in[1];
    const float* weight    = (const float*)d_in[2];
    const float* om_weight = (const float*)d_in[3];
    const float* om_bias   = (const float*)d_in[4];
    float* out = (float*)d_out;
    short* wss = (short*)d_ws;
    unsigned short* catT = (unsigned short*)(wss + CATT_OFF);

    hipLaunchKernelGGL(prep_kernel, dim3(800), dim3(256), 0, stream,
                       feat, deg, catT, weight, om_weight,
                       wss, wss + WO_PK_OFF);
    hipLaunchKernelGGL(fused_kernel, dim3(512), dim3(256), 0, stream,
                       catT, wss, wss + WO_PK_OFF, om_bias, out);
}

// Round 3
// 115.818 us; speedup vs baseline: 1.0298x; 1.0298x over previous
//
#include <hip/hip_runtime.h>
#include <math.h>

// B=8, C=64, H=W=64, O=64, K=3, KK=9, HW=4096
// Fully fused formulation, mfma_f32_16x16x32_bf16 (bf16 in, fp32 acc).
// One wave owns 16 pixels (one h-row segment) and computes om (K=1152) then
// the deformable conv (K=576) with NO cross-wave communication.
// Operand orientation (HW-validated in earlier rounds):
//   A = weights:  lane(l16,lq) holds W[m = tile*16+l16][k = step*32+lq*8+j]
//   B = samples:  lane(l16,lq) holds S[k = step*32+lq*8+j][n = px(l16)]
//   C/D: col(=px) = lane&15, row(=m) = (lane>>4)*4 + reg
//
// ws layout (shorts):
//   [0,     36864)  wd_pk : Wd A-frag-packed, idx=((ks*4+lq)*64+o)*8+j,
//                   ks=t*2+qh (18), k=t*64+qh*32+lq*8+j -> weight[o][c][t]
//   [36864, 73728)  wo_pk : Wo A-frag-packed, idx=((ks2*4+lq)*32+oc)*8+j,
//                   ks2=quarter*9+t (36), cg=quarter*32+lq*8+j; oc>=27 -> 0
//   [73728, 73728+4194304)  catT bf16[b][hw][128]  (feat c0..63, deg c64..127)
//
// R3: occupancy is GRID-limited (512 blocks = 2 blocks/CU = 2 waves/SIMD),
// so R1's 81KB LDS cost nothing -> restore lwd staging (phase-3 A-frags via
// ds_read_b128, off the vmem pipe). Keep cvt_pk blend + merged prep (R1) and
// the 8-gather-per-tap hoist (R2) -- now unconfounded: gathers are the ONLY
// vmem traffic in the phase-3 loop.
#define WO_PK_OFF 36864
#define CATT_OFF  73728

typedef short  short8  __attribute__((ext_vector_type(8)));
typedef float  float4v __attribute__((ext_vector_type(4)));
typedef unsigned int uint4v __attribute__((ext_vector_type(4)));

static __device__ __forceinline__ short f2bf(float f) {
    unsigned int u = __builtin_bit_cast(unsigned int, f);
    u += 0x7FFFu + ((u >> 16) & 1u);   // round-to-nearest-even
    return (short)(u >> 16);
}
static __device__ __forceinline__ float bf2f(unsigned short u) {
    return __builtin_bit_cast(float, (unsigned int)u << 16);
}
// pack 2 fp32 -> 2 bf16 (RNE), one instruction. lo -> D[15:0], hi -> D[31:16]
static __device__ __forceinline__ unsigned int cvt_pk_bf16(float lo, float hi) {
    unsigned int r;
    asm("v_cvt_pk_bf16_f32 %0, %1, %2" : "=v"(r) : "v"(lo), "v"(hi));
    return r;
}

// Merged prep: blocks [0,512) transpose catT, blocks [512,800) pack weights.
// Transpose: block=(b,h): 64 pixels x 128 channels, LDS round-trip, row pad
// 136 shorts (16B-aligned b128 reads, ~2-way banks).
__global__ __launch_bounds__(256) void prep_kernel(
    const float* __restrict__ feat, const float* __restrict__ deg,
    unsigned short* __restrict__ catT,
    const float* __restrict__ weight, const float* __restrict__ om_weight,
    short* __restrict__ wd_pk, short* __restrict__ wo_pk)
{
    __shared__ unsigned short T[64 * 136];     // 17,408 B
    const int tid = threadIdx.x;

    if (blockIdx.x >= 512) {                   // ---- weight packing ----
        int idx = (blockIdx.x - 512) * 256 + tid;   // covers exactly 73728
        if (idx < 36864) {
            int j = idx & 7, o = (idx >> 3) & 63, lq = (idx >> 9) & 3, ks = idx >> 11;
            int t = ks >> 1, c = (ks & 1) * 32 + lq * 8 + j;
            wd_pk[idx] = f2bf(weight[(o * 64 + c) * 9 + t]);
        } else {
            int e = idx - 36864;
            int j = e & 7, oc = (e >> 3) & 31, lq = (e >> 8) & 3, ks2 = e >> 10;
            int quarter = ks2 / 9, t = ks2 - quarter * 9;
            int cg = quarter * 32 + lq * 8 + j;
            wo_pk[e] = (oc < 27) ? f2bf(om_weight[(oc * 128 + cg) * 9 + t])
                                 : (short)0;
        }
        return;
    }

    // ---- transpose ----
    const int b = blockIdx.x >> 6, h = blockIdx.x & 63;
    const int lane = tid & 63, wv = tid >> 6;
#pragma unroll
    for (int cc = 0; cc < 32; cc++) {
        int c = wv * 32 + cc;                  // wave-uniform
        const float* src = (c < 64)
            ? (feat + (size_t)(b * 64 + c) * 4096)
            : (deg  + (size_t)(b * 64 + (c - 64)) * 4096);
        T[lane * 136 + c] = (unsigned short)f2bf(src[h * 64 + lane]);
    }
    __syncthreads();
    const int px = tid >> 2, seg = tid & 3;
    unsigned short* dst = catT + (size_t)(b * 4096 + h * 64 + px) * 128 + seg * 32;
#pragma unroll
    for (int j = 0; j < 4; j++)
        *(uint4*)(dst + j * 8) = *(const uint4*)&T[px * 136 + seg * 32 + j * 8];
}

// The fused kernel. gw = wave id in [0,2048): b = gw>>8, 16-px tile = gw&255.
// Phase 0: cooperative stage of wd_pk (72KB) into LDS (drains under the
// single barrier; occupancy unaffected -- grid-limited at 2 blocks/CU).
// Phase 1 (omconv): 36 K-steps, 2 MFMAs each. Phase 2: wave-private LDS
// transpose C-layout -> per-pixel omv[27] (+bias), one barrier. Phase 3
// (deform): 9 taps; 8 corner gathers issued up front (only vmem in loop),
// pairwise bilinear blend + cvt_pk pack, A-frags via ds_read_b128, 8 MFMAs.
__global__ __launch_bounds__(256) void fused_kernel(
    const unsigned short* __restrict__ catT, const short* __restrict__ wd_pk,
    const short* __restrict__ wo_pk, const float* __restrict__ om_bias,
    float* __restrict__ out)
{
    __shared__ __align__(16) short lwd[36864];   // 73,728 B: wd_pk mirror
    __shared__ __align__(16) float Tsm[4 * 448]; // 7,168 B (per-wave 16x28)
    const int tid = threadIdx.x;
    const int lane = tid & 63, wv = tid >> 6;
    const int l16 = lane & 15, lq = lane >> 4;
    const int gw = blockIdx.x * 4 + wv;
    const int b = gw >> 8, tile = gw & 255;
    const int h = tile >> 2, w0 = (tile & 3) << 4;
    const int pxx = w0 + l16;                  // this lane's pixel x
    const unsigned short* cb = catT + (size_t)b * 4096 * 128;

    // ------ phase 0: stage wd_pk -> LDS (4608 uint4, 18 per thread) ------
    {
        const uint4* src = (const uint4*)wd_pk;
        uint4* dst = (uint4*)lwd;
#pragma unroll
        for (int i = 0; i < 18; i++)
            dst[i * 256 + tid] = src[i * 256 + tid];
    }

    // ---------------- phase 1: om conv ----------------
    float4v oacc0 = {0.f, 0.f, 0.f, 0.f};
    float4v oacc1 = {0.f, 0.f, 0.f, 0.f};
    const short8 zf = {0, 0, 0, 0, 0, 0, 0, 0};
#pragma unroll
    for (int quarter = 0; quarter < 4; quarter++) {
#pragma unroll
        for (int t = 0; t < 9; t++) {
            const int ky = t / 3, kx = t - ky * 3;
            const int yy = h - 1 + ky;         // wave-uniform
            if (yy >= 0 && yy <= 63) {
                int xx = pxx - 1 + kx;
                bool okx = (xx >= 0) & (xx <= 63);
                int xc = min(max(xx, 0), 63);
                short8 bfr = *(const short8*)(cb + (yy * 64 + xc) * 128
                                                 + quarter * 32 + lq * 8);
                bfr = okx ? bfr : zf;
                const short8* Ap = (const short8*)(wo_pk
                    + (size_t)((quarter * 9 + t) * 4 + lq) * 256);
                oacc0 = __builtin_amdgcn_mfma_f32_16x16x32_bf16(
                    Ap[l16], bfr, oacc0, 0, 0, 0);
                oacc1 = __builtin_amdgcn_mfma_f32_16x16x32_bf16(
                    Ap[16 + l16], bfr, oacc1, 0, 0, 0);
            }
        }
    }

    // ------- phase 2: wave-private transpose -> omv[27] -------
    float* Tw = Tsm + wv * 448;                // 16 rows x 28 floats
#pragma unroll
    for (int r = 0; r < 4; r++) {
        Tw[l16 * 28 + lq * 4 + r] = oacc0[r];             // oc = lq*4+r
        if (lq < 3)
            Tw[l16 * 28 + 16 + lq * 4 + r] = oacc1[r];    // oc = 16+lq*4+r <= 27
    }
    __syncthreads();   // orders: lwd staging (all threads) + Tsm w->r
    float omv[28];
#pragma unroll
    for (int jj = 0; jj < 7; jj++)
        *(float4v*)&omv[jj * 4] = *(const float4v*)&Tw[l16 * 28 + jj * 4];
#pragma unroll
    for (int j = 0; j < 27; j++) omv[j] += om_bias[j];

    // ---------------- phase 3: deformable conv ----------------
    float4v acc[4];
#pragma unroll
    for (int mt = 0; mt < 4; mt++) acc[mt] = (float4v){0.f, 0.f, 0.f, 0.f};
#pragma unroll
    for (int t = 0; t < 9; t++) {
        const int ky = t / 3, kx = t - ky * 3;
        float dy = omv[2 * t], dx = omv[2 * t + 1];
        float mm = 1.f / (1.f + __expf(-omv[18 + t]));   // sigmoid(mask)
        float yf = (float)(h - 1 + ky) + dy;
        float xf = (float)(pxx - 1 + kx) + dx;
        float fy = floorf(yf), fx = floorf(xf);
        int y0 = (int)fy, x0 = (int)fx;
        float wy = yf - fy, wx = xf - fx;
        bool vy0 = (y0 >= 0) & (y0 < 64);
        bool vy1 = (y0 >= -1) & (y0 < 63);
        bool vx0 = (x0 >= 0) & (x0 < 64);
        bool vx1 = (x0 >= -1) & (x0 < 63);
        float a0 = (1.f - wy) * mm, a1 = wy * mm;
        float W00 = a0 * (1.f - wx) * (float)(vy0 & vx0);
        float W01 = a0 * wx         * (float)(vy0 & vx1);
        float W10 = a1 * (1.f - wx) * (float)(vy1 & vx0);
        float W11 = a1 * wx         * (float)(vy1 & vx1);
        // taps clamped INDEPENDENTLY: clamp(y0+1), not clamp(y0)+1
        int iy0 = min(max(y0, 0), 63),     ix0 = min(max(x0, 0), 63);
        int iy1 = min(max(y0 + 1, 0), 63), ix1 = min(max(x0 + 1, 0), 63);
        int O00 = (iy0 * 64 + ix0) * 128, O01 = (iy0 * 64 + ix1) * 128;
        int O10 = (iy1 * 64 + ix0) * 128, O11 = (iy1 * 64 + ix1) * 128;

        // issue ALL 8 corner gathers (both ch-halves) before blending: the
        // only vmem traffic in this loop; 8 scattered b128 loads in flight
        uint4v u0[4], u1[4];
        {
            const int c0 = lq * 8, c1 = 32 + lq * 8;
            u0[0] = *(const uint4v*)(cb + O00 + c0);
            u0[1] = *(const uint4v*)(cb + O01 + c0);
            u0[2] = *(const uint4v*)(cb + O10 + c0);
            u0[3] = *(const uint4v*)(cb + O11 + c0);
            u1[0] = *(const uint4v*)(cb + O00 + c1);
            u1[1] = *(const uint4v*)(cb + O01 + c1);
            u1[2] = *(const uint4v*)(cb + O10 + c1);
            u1[3] = *(const uint4v*)(cb + O11 + c1);
        }
#pragma unroll
        for (int qh = 0; qh < 2; qh++) {
            uint4v u00 = qh ? u1[0] : u0[0];
            uint4v u01 = qh ? u1[1] : u0[1];
            uint4v u10 = qh ? u1[2] : u0[2];
            uint4v u11 = qh ? u1[3] : u0[3];
            uint4v br;
#pragma unroll
            for (int p = 0; p < 4; p++) {   // channel pair (2p lo, 2p+1 hi)
                float l00 = __builtin_bit_cast(float, u00[p] << 16);
                float h00 = __builtin_bit_cast(float, u00[p] & 0xffff0000u);
                float l01 = __builtin_bit_cast(float, u01[p] << 16);
                float h01 = __builtin_bit_cast(float, u01[p] & 0xffff0000u);
                float l10 = __builtin_bit_cast(float, u10[p] << 16);
                float h10 = __builtin_bit_cast(float, u10[p] & 0xffff0000u);
                float l11 = __builtin_bit_cast(float, u11[p] << 16);
                float h11 = __builtin_bit_cast(float, u11[p] & 0xffff0000u);
                float slo = W00 * l00 + W01 * l01 + W10 * l10 + W11 * l11;
                float shi = W00 * h00 + W01 * h01 + W10 * h10 + W11 * h11;
                br[p] = cvt_pk_bf16(slo, shi);
            }
            short8 bfr = __builtin_bit_cast(short8, br);
            const short8* Dp = (const short8*)(lwd
                + (size_t)((t * 2 + qh) * 4 + lq) * 512);
            acc[0] = __builtin_amdgcn_mfma_f32_16x16x32_bf16(
                Dp[l16], bfr, acc[0], 0, 0, 0);
            acc[1] = __builtin_amdgcn_mfma_f32_16x16x32_bf16(
                Dp[16 + l16], bfr, acc[1], 0, 0, 0);
            acc[2] = __builtin_amdgcn_mfma_f32_16x16x32_bf16(
                Dp[32 + l16], bfr, acc[2], 0, 0, 0);
            acc[3] = __builtin_amdgcn_mfma_f32_16x16x32_bf16(
                Dp[48 + l16], bfr, acc[3], 0, 0, 0);
        }
    }

    // store: o = mt*16 + lq*4 + r, px = w0 + l16 (4-seg coalesced)
    float* ob = out + (size_t)(b * 64) * 4096 + h * 64 + w0 + l16;
#pragma unroll
    for (int mt = 0; mt < 4; mt++)
#pragma unroll
        for (int r = 0; r < 4; r++)
            ob[(mt * 16 + lq * 4 + r) * 4096] = acc[mt][r];
}

extern "C" void kernel_launch(void* const* d_in, const int* in_sizes, int n_in,
                              void* d_out, int out_size, void* d_ws, size_t ws_size,
                              hipStream_t stream)
{
    const float* feat      = (const float*)d_in[0];
    const float* deg       = (const float*)d_in[1];
    const float* weight    = (const float*)d_in[2];
    const float* om_weight = (const float*)d_in[3];
    const float* om_bias   = (const float*)d_in[4];
    float* out = (float*)d_out;
    short* wss = (short*)d_ws;
    unsigned short* catT = (unsigned short*)(wss + CATT_OFF);

    hipLaunchKernelGGL(prep_kernel, dim3(800), dim3(256), 0, stream,
                       feat, deg, catT, weight, om_weight,
                       wss, wss + WO_PK_OFF);
    hipLaunchKernelGGL(fused_kernel, dim3(512), dim3(256), 0, stream,
                       catT, wss, wss + WO_PK_OFF, om_bias, out);
}

// Round 4
// 114.715 us; speedup vs baseline: 1.0397x; 1.0096x over previous
//
#include <hip/hip_runtime.h>
#include <math.h>

// B=8, C=64, H=W=64, O=64, K=3, KK=9, HW=4096
// Fully fused formulation, mfma_f32_16x16x32_bf16 (bf16 in, fp32 acc).
// One wave owns 16 pixels (one h-row segment) and computes om (K=1152) then
// the deformable conv (K=576) with NO cross-wave communication.
// Operand orientation (HW-validated in earlier rounds):
//   A = weights:  lane(l16,lq) holds W[m = tile*16+l16][k = step*32+lq*8+j]
//   B = samples:  lane(l16,lq) holds S[k = step*32+lq*8+j][n = px(l16)]
//   C/D: col(=px) = lane&15, row(=m) = (lane>>4)*4 + reg
//
// ws layout (shorts):
//   [0,     36864)  wd_pk : Wd A-frag-packed, idx=((ks*4+lq)*64+o)*8+j
//   [36864, 73728)  wo_pk : Wo A-frag-packed, idx=((ks2*4+lq)*32+oc)*8+j
//   [73728, 73728+4194304)  catT bf16[b][hw][128]  (feat c0..63, deg c64..127)
//   [4268032, 4268160)      zr : 128 zero shorts (OOB-x load target)
//
// R4 (on top of R3's best-measured config): occupancy is grid-pinned at
// 2 waves/SIMD, so VGPRs<=256 are free -> buy ILP.
//  (1) phase-3 pipelined 1 tap ahead (next tap's 8 gathers in flight across
//      current tap's blend+MFMA; vmcnt never drains idle),
//  (2) phase-1 t-outer/quarter-inner (4xb128 per lane on one pixel line,
//      bounds once per t),
//  (3) OOB-x handled by zero-page pointer select instead of 16 cndmask/t.
#define WO_PK_OFF 36864
#define CATT_OFF  73728
#define ZR_OFF    4268032

typedef short  short8  __attribute__((ext_vector_type(8)));
typedef float  float4v __attribute__((ext_vector_type(4)));
typedef unsigned int uint4v __attribute__((ext_vector_type(4)));

static __device__ __forceinline__ short f2bf(float f) {
    unsigned int u = __builtin_bit_cast(unsigned int, f);
    u += 0x7FFFu + ((u >> 16) & 1u);   // round-to-nearest-even
    return (short)(u >> 16);
}
// pack 2 fp32 -> 2 bf16 (RNE), one instruction. lo -> D[15:0], hi -> D[31:16]
static __device__ __forceinline__ unsigned int cvt_pk_bf16(float lo, float hi) {
    unsigned int r;
    asm("v_cvt_pk_bf16_f32 %0, %1, %2" : "=v"(r) : "v"(lo), "v"(hi));
    return r;
}

// Merged prep: blocks [0,512) transpose catT, blocks [512,801) pack weights
// (+ block 800 zeroes the 128-short zero page).
__global__ __launch_bounds__(256) void prep_kernel(
    const float* __restrict__ feat, const float* __restrict__ deg,
    unsigned short* __restrict__ catT,
    const float* __restrict__ weight, const float* __restrict__ om_weight,
    short* __restrict__ wd_pk, short* __restrict__ wo_pk)
{
    __shared__ unsigned short T[64 * 136];     // 17,408 B
    const int tid = threadIdx.x;

    if (blockIdx.x >= 512) {                   // ---- weight packing ----
        int idx = (blockIdx.x - 512) * 256 + tid;
        if (idx < 36864) {
            int j = idx & 7, o = (idx >> 3) & 63, lq = (idx >> 9) & 3, ks = idx >> 11;
            int t = ks >> 1, c = (ks & 1) * 32 + lq * 8 + j;
            wd_pk[idx] = f2bf(weight[(o * 64 + c) * 9 + t]);
        } else if (idx < 73728) {
            int e = idx - 36864;
            int j = e & 7, oc = (e >> 3) & 31, lq = (e >> 8) & 3, ks2 = e >> 10;
            int quarter = ks2 / 9, t = ks2 - quarter * 9;
            int cg = quarter * 32 + lq * 8 + j;
            wo_pk[e] = (oc < 27) ? f2bf(om_weight[(oc * 128 + cg) * 9 + t])
                                 : (short)0;
        } else if (idx < 73856) {
            wd_pk[ZR_OFF + (idx - 73728)] = 0;   // zero page (wd_pk == ws base)
        }
        return;
    }

    // ---- transpose ----
    const int b = blockIdx.x >> 6, h = blockIdx.x & 63;
    const int lane = tid & 63, wv = tid >> 6;
#pragma unroll
    for (int cc = 0; cc < 32; cc++) {
        int c = wv * 32 + cc;                  // wave-uniform
        const float* src = (c < 64)
            ? (feat + (size_t)(b * 64 + c) * 4096)
            : (deg  + (size_t)(b * 64 + (c - 64)) * 4096);
        T[lane * 136 + c] = (unsigned short)f2bf(src[h * 64 + lane]);
    }
    __syncthreads();
    const int px = tid >> 2, seg = tid & 3;
    unsigned short* dst = catT + (size_t)(b * 4096 + h * 64 + px) * 128 + seg * 32;
#pragma unroll
    for (int j = 0; j < 4; j++)
        *(uint4*)(dst + j * 8) = *(const uint4*)&T[px * 136 + seg * 32 + j * 8];
}

// The fused kernel. gw = wave id in [0,2048): b = gw>>8, 16-px tile = gw&255.
// Phase 0: cooperative stage of wd_pk (72KB) into LDS. Phase 1 (omconv):
// 9 taps x {4xb128 line load, 4 quarters x 2 MFMA}. Phase 2: wave-private
// LDS transpose -> omv[27] (+bias), one barrier. Phase 3 (deform): 9 taps
// software-pipelined 1 ahead: issue tap t+1's 8 gathers, then blend tap t
// (pairwise bf16 + cvt_pk) and 8 MFMAs with A-frags via ds_read_b128.
__global__ __launch_bounds__(256, 2) void fused_kernel(
    const unsigned short* __restrict__ catT, const short* __restrict__ wd_pk,
    const short* __restrict__ wo_pk, const float* __restrict__ om_bias,
    float* __restrict__ out)
{
    __shared__ __align__(16) short lwd[36864];   // 73,728 B: wd_pk mirror
    __shared__ __align__(16) float Tsm[4 * 448]; // 7,168 B (per-wave 16x28)
    const int tid = threadIdx.x;
    const int lane = tid & 63, wv = tid >> 6;
    const int l16 = lane & 15, lq = lane >> 4;
    const int gw = blockIdx.x * 4 + wv;
    const int b = gw >> 8, tile = gw & 255;
    const int h = tile >> 2, w0 = (tile & 3) << 4;
    const int pxx = w0 + l16;                  // this lane's pixel x
    const unsigned short* cb = catT + (size_t)b * 4096 * 128;
    const unsigned short* zbase = catT + (size_t)4194304;  // 128 zero shorts

    // ------ phase 0: stage wd_pk -> LDS (4608 uint4, 18 per thread) ------
    {
        const uint4* src = (const uint4*)wd_pk;
        uint4* dst = (uint4*)lwd;
#pragma unroll
        for (int i = 0; i < 18; i++)
            dst[i * 256 + tid] = src[i * 256 + tid];
    }

    // ---------------- phase 1: om conv (t outer, quarter inner) ----------
    float4v oacc0 = {0.f, 0.f, 0.f, 0.f};
    float4v oacc1 = {0.f, 0.f, 0.f, 0.f};
#pragma unroll
    for (int t = 0; t < 9; t++) {
        const int ky = t / 3, kx = t - ky * 3;
        const int yy = h - 1 + ky;             // wave-uniform
        if (yy >= 0 && yy <= 63) {
            int xx = pxx - 1 + kx;
            bool okx = (xx >= 0) & (xx <= 63);
            const unsigned short* pl = okx
                ? (cb + (yy * 64 + xx) * 128 + lq * 8)
                : (zbase + lq * 8);            // zero page: bfr==0
            short8 bq0 = *(const short8*)(pl);
            short8 bq1 = *(const short8*)(pl + 32);
            short8 bq2 = *(const short8*)(pl + 64);
            short8 bq3 = *(const short8*)(pl + 96);
#pragma unroll
            for (int quarter = 0; quarter < 4; quarter++) {
                short8 bfr = quarter == 0 ? bq0 : quarter == 1 ? bq1
                           : quarter == 2 ? bq2 : bq3;
                const short8* Ap = (const short8*)(wo_pk
                    + (size_t)((quarter * 9 + t) * 4 + lq) * 256);
                oacc0 = __builtin_amdgcn_mfma_f32_16x16x32_bf16(
                    Ap[l16], bfr, oacc0, 0, 0, 0);
                oacc1 = __builtin_amdgcn_mfma_f32_16x16x32_bf16(
                    Ap[16 + l16], bfr, oacc1, 0, 0, 0);
            }
        }
    }

    // ------- phase 2: wave-private transpose -> omv[27] -------
    float* Tw = Tsm + wv * 448;                // 16 rows x 28 floats
#pragma unroll
    for (int r = 0; r < 4; r++) {
        Tw[l16 * 28 + lq * 4 + r] = oacc0[r];             // oc = lq*4+r
        if (lq < 3)
            Tw[l16 * 28 + 16 + lq * 4 + r] = oacc1[r];    // oc = 16+lq*4+r <= 27
    }
    __syncthreads();   // orders: lwd staging (all threads) + Tsm w->r
    float omv[28];
#pragma unroll
    for (int jj = 0; jj < 7; jj++)
        *(float4v*)&omv[jj * 4] = *(const float4v*)&Tw[l16 * 28 + jj * 4];
#pragma unroll
    for (int j = 0; j < 27; j++) omv[j] += om_bias[j];

    // ------------- phase 3: deformable conv, 1-tap-ahead pipeline --------
    float4v acc[4];
#pragma unroll
    for (int mt = 0; mt < 4; mt++) acc[mt] = (float4v){0.f, 0.f, 0.f, 0.f};

    float  Wt[2][4];
    uint4v u0[2][4], u1[2][4];

    // compute tap t's weights + issue its 8 gathers into slot s
    auto prep_tap = [&](int t, int s) {
        const int ky = t / 3, kx = t - ky * 3;
        float dy = omv[2 * t], dx = omv[2 * t + 1];
        float mm = 1.f / (1.f + __expf(-omv[18 + t]));   // sigmoid(mask)
        float yf = (float)(h - 1 + ky) + dy;
        float xf = (float)(pxx - 1 + kx) + dx;
        float fy = floorf(yf), fx = floorf(xf);
        int y0 = (int)fy, x0 = (int)fx;
        float wy = yf - fy, wx = xf - fx;
        bool vy0 = (y0 >= 0) & (y0 < 64);
        bool vy1 = (y0 >= -1) & (y0 < 63);
        bool vx0 = (x0 >= 0) & (x0 < 64);
        bool vx1 = (x0 >= -1) & (x0 < 63);
        float a0 = (1.f - wy) * mm, a1 = wy * mm;
        Wt[s][0] = a0 * (1.f - wx) * (float)(vy0 & vx0);
        Wt[s][1] = a0 * wx         * (float)(vy0 & vx1);
        Wt[s][2] = a1 * (1.f - wx) * (float)(vy1 & vx0);
        Wt[s][3] = a1 * wx         * (float)(vy1 & vx1);
        // taps clamped INDEPENDENTLY: clamp(y0+1), not clamp(y0)+1
        int iy0 = min(max(y0, 0), 63),     ix0 = min(max(x0, 0), 63);
        int iy1 = min(max(y0 + 1, 0), 63), ix1 = min(max(x0 + 1, 0), 63);
        int O00 = (iy0 * 64 + ix0) * 128, O01 = (iy0 * 64 + ix1) * 128;
        int O10 = (iy1 * 64 + ix0) * 128, O11 = (iy1 * 64 + ix1) * 128;
        const int c0 = lq * 8, c1 = 32 + lq * 8;
        u0[s][0] = *(const uint4v*)(cb + O00 + c0);
        u0[s][1] = *(const uint4v*)(cb + O01 + c0);
        u0[s][2] = *(const uint4v*)(cb + O10 + c0);
        u0[s][3] = *(const uint4v*)(cb + O11 + c0);
        u1[s][0] = *(const uint4v*)(cb + O00 + c1);
        u1[s][1] = *(const uint4v*)(cb + O01 + c1);
        u1[s][2] = *(const uint4v*)(cb + O10 + c1);
        u1[s][3] = *(const uint4v*)(cb + O11 + c1);
    };

    prep_tap(0, 0);
#pragma unroll
    for (int t = 0; t < 9; t++) {
        const int s = t & 1;
        if (t < 8) prep_tap(t + 1, s ^ 1);     // next tap's loads in flight
        const float W00 = Wt[s][0], W01 = Wt[s][1];
        const float W10 = Wt[s][2], W11 = Wt[s][3];
#pragma unroll
        for (int qh = 0; qh < 2; qh++) {
            uint4v u00 = qh ? u1[s][0] : u0[s][0];
            uint4v u01 = qh ? u1[s][1] : u0[s][1];
            uint4v u10 = qh ? u1[s][2] : u0[s][2];
            uint4v u11 = qh ? u1[s][3] : u0[s][3];
            uint4v br;
#pragma unroll
            for (int p = 0; p < 4; p++) {   // channel pair (2p lo, 2p+1 hi)
                float l00 = __builtin_bit_cast(float, u00[p] << 16);
                float h00 = __builtin_bit_cast(float, u00[p] & 0xffff0000u);
                float l01 = __builtin_bit_cast(float, u01[p] << 16);
                float h01 = __builtin_bit_cast(float, u01[p] & 0xffff0000u);
                float l10 = __builtin_bit_cast(float, u10[p] << 16);
                float h10 = __builtin_bit_cast(float, u10[p] & 0xffff0000u);
                float l11 = __builtin_bit_cast(float, u11[p] << 16);
                float h11 = __builtin_bit_cast(float, u11[p] & 0xffff0000u);
                float slo = W00 * l00 + W01 * l01 + W10 * l10 + W11 * l11;
                float shi = W00 * h00 + W01 * h01 + W10 * h10 + W11 * h11;
                br[p] = cvt_pk_bf16(slo, shi);
            }
            short8 bfr = __builtin_bit_cast(short8, br);
            const short8* Dp = (const short8*)(lwd
                + (size_t)((t * 2 + qh) * 4 + lq) * 512);
            acc[0] = __builtin_amdgcn_mfma_f32_16x16x32_bf16(
                Dp[l16], bfr, acc[0], 0, 0, 0);
            acc[1] = __builtin_amdgcn_mfma_f32_16x16x32_bf16(
                Dp[16 + l16], bfr, acc[1], 0, 0, 0);
            acc[2] = __builtin_amdgcn_mfma_f32_16x16x32_bf16(
                Dp[32 + l16], bfr, acc[2], 0, 0, 0);
            acc[3] = __builtin_amdgcn_mfma_f32_16x16x32_bf16(
                Dp[48 + l16], bfr, acc[3], 0, 0, 0);
        }
    }

    // store: o = mt*16 + lq*4 + r, px = w0 + l16 (4-seg coalesced)
    float* ob = out + (size_t)(b * 64) * 4096 + h * 64 + w0 + l16;
#pragma unroll
    for (int mt = 0; mt < 4; mt++)
#pragma unroll
        for (int r = 0; r < 4; r++)
            ob[(mt * 16 + lq * 4 + r) * 4096] = acc[mt][r];
}

extern "C" void kernel_launch(void* const* d_in, const int* in_sizes, int n_in,
                              void* d_out, int out_size, void* d_ws, size_t ws_size,
                              hipStream_t stream)
{
    const float* feat      = (const float*)d_in[0];
    const float* deg       = (const float*)d_in[1];
    const float* weight    = (const float*)d_in[2];
    const float* om_weight = (const float*)d_in[3];
    const float* om_bias   = (const float*)d_in[4];
    float* out = (float*)d_out;
    short* wss = (short*)d_ws;
    unsigned short* catT = (unsigned short*)(wss + CATT_OFF);

    hipLaunchKernelGGL(prep_kernel, dim3(801), dim3(256), 0, stream,
                       feat, deg, catT, weight, om_weight,
                       wss, wss + WO_PK_OFF);
    hipLaunchKernelGGL(fused_kernel, dim3(512), dim3(256), 0, stream,
                       catT, wss, wss + WO_PK_OFF, om_bias, out);
}